// Round 10
// baseline (312.104 us; speedup 1.0000x reference)
//
#include <hip/hip_runtime.h>

#define LOSS_OFF 8388608
#define IDX_OFF  8388609

// ws layout (bytes)
#define WS_SEE   0          // float[1024]
#define WS_SXX   4096       // float[32768]            -> 135168
#define WS_KEY   135168     // u64[32768]              -> 397312
#define WS_LOSS  397312     // double
#define WS_ET    397440     // eT[c][k] float[256][1024] = 1 MB (64B-aligned)

#define FLT_BIG  3.402823466e+38f

// numpy pairwise_sum of 256 squared elements, bit-exact (see round-2 notes).
__device__ __forceinline__ float np_sumsq256(const float* __restrict__ p, int stride) {
    float s[2];
#pragma unroll
    for (int half = 0; half < 2; half++) {
        const float* a = p + half * 128 * stride;
        float r[8];
#pragma unroll
        for (int l = 0; l < 8; l++) {
            float v = a[l * stride];
            float sq = v * v;
            asm volatile("" : "+v"(sq));   // forbid fma contraction into the add chain
            r[l] = sq;
        }
#pragma unroll
        for (int i = 8; i < 128; i += 8) {
#pragma unroll
            for (int l = 0; l < 8; l++) {
                float v = a[(i + l) * stride];
                float sq = v * v;
                asm volatile("" : "+v"(sq));
                r[l] = r[l] + sq;
            }
        }
        s[half] = ((r[0] + r[1]) + (r[2] + r[3])) + ((r[4] + r[5]) + (r[6] + r[7]));
    }
    return s[0] + s[1];
}

__device__ __forceinline__ unsigned int f32_sortable(float m) {
    unsigned int u = __float_as_uint(m);
    return u ^ (((unsigned int)((int)u >> 31)) | 0x80000000u);
}

// ---------------- k0: codebook ||e||^2 (np semantics) + init ----------------
__global__ __launch_bounds__(256) void k0_see(const float* __restrict__ emb,
                                              float* __restrict__ see,
                                              double* __restrict__ loss) {
    const int k = blockIdx.x * 256 + threadIdx.x;   // grid 4 x 256
    see[k] = np_sumsq256(emb + (size_t)k * 256, 1);
    if (k == 0) { *loss = 0.0; }
}

// ---------------- k_et: transpose codebook -> eT[c][k] ----------------
// grid 64 x 256: block handles 16 codes x all 256 c.
__global__ __launch_bounds__(256) void k_et(const float* __restrict__ emb,
                                            float* __restrict__ eT) {
    __shared__ float T[256][17];
    const int t  = threadIdx.x;
    const int k0 = blockIdx.x << 4;
    const int kr = t >> 4, cs = (t & 15) << 4;
#pragma unroll
    for (int j = 0; j < 4; j++) {
        const float4 v = *(const float4*)(emb + (size_t)(k0 + kr) * 256 + cs + j * 4);
        T[cs + j * 4 + 0][kr] = v.x;
        T[cs + j * 4 + 1][kr] = v.y;
        T[cs + j * 4 + 2][kr] = v.z;
        T[cs + j * 4 + 3][kr] = v.w;
    }
    __syncthreads();
    float* dst = eT + (size_t)t * 1024 + k0;   // row c = t, 16 consecutive codes
#pragma unroll
    for (int j = 0; j < 4; j++) {
        float4 v;
        v.x = T[t][j * 4 + 0]; v.y = T[t][j * 4 + 1];
        v.z = T[t][j * 4 + 2]; v.w = T[t][j * 4 + 3];
        *(float4*)(dst + j * 4) = v;
    }
}

// ---------------- k_sxx: per-row ||x||^2 (np semantics) + key init ----------------
__global__ __launch_bounds__(64) void k_sxx(const float* __restrict__ x,
                                            float* __restrict__ sxx,
                                            unsigned long long* __restrict__ key) {
    const int n = blockIdx.x * 64 + threadIdx.x;    // grid 512 x 64
    const int b = n >> 10, hw = n & 1023;
    sxx[n] = np_sumsq256(x + (size_t)b * 262144 + hw, 1024);
    key[n] = ~0ull;
}

// ---------------- k1: SGPR-B distance + argmin ----------------
// grid 4096, block 256 (4 waves). Decode q=bid>>9, rs=bid&511 so bid%8=rs%8:
// the 8 code-blocks of one row-set land on ONE XCD -> x-slice (64 KB) is an
// L2 hit (~200cy) for 7 of 8 readers instead of an L3 round-trip (~500cy).
// Wave: 64 rows (lane-per-row) x 32 codes (wave-uniform -> SGPR b operands).
// av[8]: explicit prefetch array -> 8 a-loads batched in flight (round 9's
// VGPR_Count=32 proved the allocator left 0 regs to batch; acc+av+addr ~56
// still fits the 8-wave/EU 64-reg budget).
// dot = sequential fp32 FMA chain over c=0..255 (dependent chain, no
// fast-math => compiler cannot reassociate; bit-matches np reference).
__global__ __launch_bounds__(256) void k1_dist(const float* __restrict__ x,
                                               const float* __restrict__ eT,
                                               const float* __restrict__ see_g,
                                               const float* __restrict__ sxx_g,
                                               unsigned long long* __restrict__ key) {
    const int t  = threadIdx.x;
    const int l  = t & 63;
    const int wv = __builtin_amdgcn_readfirstlane(t >> 6);   // 0..3, uniform
    const int bid = blockIdx.x;
    const int q   = bid >> 9;                 // code-block (128 codes)
    const int rs  = bid & 511;                // row-set (64 rows)
    const int k0  = q * 128 + wv * 32;        // wave's 32 codes (uniform)
    const int b   = rs >> 4;
    const int hw0 = (rs & 15) << 6;
    const int n   = rs * 64 + l;

    const float* __restrict__ xc = x  + (size_t)b * 262144 + hw0 + l;  // +1024/c
    const float* __restrict__ ec = eT + k0;                            // +1024/c

    float acc[32];
#pragma unroll
    for (int j = 0; j < 32; j++) acc[j] = 0.f;

    for (int cc = 0; cc < 256; cc += 8) {
        float av[8];
#pragma unroll
        for (int u = 0; u < 8; ++u)
            av[u] = xc[(size_t)(cc + u) << 10];
#pragma unroll
        for (int u = 0; u < 8; ++u) {
#pragma unroll
            for (int j = 0; j < 32; ++j)
                acc[j] = fmaf(av[u], ec[((size_t)(cc + u) << 10) + j], acc[j]);
        }
    }

    // fold: q = fl(fl(sxx - 2*dot) + see); packed (sortable(q),k) min ==
    // min distance then lowest index == numpy first-occurrence argmin.
    const float sx = sxx_g[n];
    unsigned long long best = ~0ull;
#pragma unroll
    for (int j = 0; j < 32; j++) {
        const float t1 = fmaf(-2.f, acc[j], sx);
        const float qd = t1 + see_g[k0 + j];
        const unsigned long long pk =
            ((unsigned long long)f32_sortable(qd) << 32) | (unsigned int)(k0 + j);
        best = pk < best ? pk : best;
    }

    // in-block reduce (4 waves) then one atomicMin per row per block
    __shared__ unsigned long long red[4][64];
    red[wv][l] = best;
    __syncthreads();
    if (t < 64) {
        unsigned long long m = red[0][t];
        m = red[1][t] < m ? red[1][t] : m;
        m = red[2][t] < m ? red[2][t] : m;
        m = red[3][t] < m ? red[3][t] : m;
        atomicMin(&key[rs * 64 + t], m);
    }
}

// ---------------- k3: gather quantized + loss partials + indices ----------------
__global__ __launch_bounds__(256) void k3_out(const float* __restrict__ x,
                                              const float* __restrict__ emb,
                                              const unsigned long long* __restrict__ key,
                                              float* __restrict__ dout,
                                              double* __restrict__ loss) {
    __shared__ float elds[32][257];
    __shared__ int   idxs[32];
    __shared__ float red[256];
    const int t  = threadIdx.x;
    const int bh = blockIdx.x;
    const int b = bh >> 5, h = bh & 31;
    if (t < 32) idxs[t] = (int)(key[(bh << 5) + t] & 0xffffffffull);
    __syncthreads();
    for (int r = 0; r < 32; r++) elds[r][t] = emb[(size_t)idxs[r] * 256 + t];
    __syncthreads();
    const int w = t & 31, cg = t >> 5;
    const size_t base = (size_t)b * 262144 + (size_t)(h * 32 + w);
    float acc = 0.f;
#pragma unroll 4
    for (int s = 0; s < 32; s++) {
        const int c = (cg << 5) + s;
        const float q  = elds[w][c];
        const float xv = x[base + (size_t)c * 1024];
        dout[base + (size_t)c * 1024] = q;
        const float d = q - xv;
        acc = fmaf(d, d, acc);
    }
    red[t] = acc;
    __syncthreads();
    for (int s = 128; s > 0; s >>= 1) {
        if (t < s) red[t] += red[t + s];
        __syncthreads();
    }
    if (t == 0) atomicAdd(loss, (double)red[0]);
    if (t < 32) dout[IDX_OFF + (bh << 5) + t] = (float)idxs[t];
}

// ---------------- k4: finalize loss ----------------
__global__ void k4_fin(const double* __restrict__ loss, float* __restrict__ dout) {
    dout[LOSS_OFF] = (float)(1.25 * (*loss) / 8388608.0);
}

extern "C" void kernel_launch(void* const* d_in, const int* in_sizes, int n_in,
                              void* d_out, int out_size, void* d_ws, size_t ws_size,
                              hipStream_t stream) {
    const float* x   = (const float*)d_in[0];
    const float* emb = (const float*)d_in[1];
    float* dout = (float*)d_out;
    char* ws = (char*)d_ws;
    float*  see  = (float*)(ws + WS_SEE);
    float*  sxx  = (float*)(ws + WS_SXX);
    unsigned long long* key = (unsigned long long*)(ws + WS_KEY);
    double* loss = (double*)(ws + WS_LOSS);
    float*  eT   = (float*)(ws + WS_ET);

    k0_see<<<4, 256, 0, stream>>>(emb, see, loss);
    k_et<<<64, 256, 0, stream>>>(emb, eT);
    k_sxx<<<512, 64, 0, stream>>>(x, sxx, key);
    k1_dist<<<4096, 256, 0, stream>>>(x, eT, see, sxx, key);
    k3_out<<<1024, 256, 0, stream>>>(x, emb, key, dout, loss);
    k4_fin<<<1, 1, 0, stream>>>(loss, dout);
}